// Round 14
// baseline (216.157 us; speedup 1.0000x reference)
//
#include <hip/hip_runtime.h>

#define N_NODES 50000
#define N_EDGES 800000
#define SCAN_NB ((N_NODES + 255) / 256)

// CSR build decomposition: 64 edge chunks x 2 node halves
#define NB_E 64
#define CH (N_EDGES / NB_E)            // 12500 edges per chunk
#define RSZ 25000                      // nodes per half-range
#define HALF_WORDS (RSZ / 2)           // 12500 u32 = 50KB LDS
#define CSRB (NB_E * 2)                // 128 blocks for hist/fill

// prep sections (no-LDS kernel: cvt + weight packs)
#define CVT_ITEMS  (N_NODES * 96 / 4)
#define CVT_NB  ((CVT_ITEMS + 255) / 256)
#define PACK1_NB 12
#define PACK2_NB 16
#define PACK3_NB 8
#define PREP_NB (CVT_NB + PACK1_NB + PACK2_NB + PACK3_NB)

#define GEMM_NB ((N_NODES + 127) / 128)   // 391

typedef __attribute__((ext_vector_type(8))) short short8;
typedef __attribute__((ext_vector_type(8))) unsigned short ushort8;
typedef __attribute__((ext_vector_type(4))) float f32x4;

__device__ __forceinline__ float bf2f(unsigned short u) {
  unsigned int x = ((unsigned int)u) << 16;
  return __builtin_bit_cast(float, x);
}
__device__ __forceinline__ unsigned short f2bf(float f) {
  unsigned int x = __builtin_bit_cast(unsigned int, f);
  unsigned int r = x + 0x7FFFu + ((x >> 16) & 1u);
  return (unsigned short)(r >> 16);
}

// ---------------- prep: cvt_x | pack_w x3 (no LDS) ----------------

__device__ __forceinline__ void pack_w_section(const float* __restrict__ Wl,
                                               const float* __restrict__ Wr,
                                               ushort* __restrict__ wcat,
                                               int K, int J2, int bid) {
  int idx = bid * 256 + threadIdx.x;
  int Jcat = 2 * J2;
  int total = (K / 8) * Jcat;
  if (idx >= total) return;
  int kk8 = idx / Jcat, j = idx % Jcat;
  const float* W = (j < J2) ? Wl : Wr;
  int jj = (j < J2) ? j : j - J2;
  ushort8 v;
  #pragma unroll
  for (int i = 0; i < 8; i++) v[i] = f2bf(W[(kk8 * 8 + i) * J2 + jj]);
  *(ushort8*)(wcat + (size_t)idx * 8) = v;
}

__global__ __launch_bounds__(256) void prep_kernel(
    const float* __restrict__ x, ushort* __restrict__ xb,
    const float* __restrict__ Wl1, const float* __restrict__ Wr1, ushort* __restrict__ wcat1,
    const float* __restrict__ Wl2, const float* __restrict__ Wr2, ushort* __restrict__ wcat2,
    const float* __restrict__ Wl3, const float* __restrict__ Wr3, ushort* __restrict__ wcat3) {
  int bid = blockIdx.x;
  if (bid < CVT_NB) {
    int i = bid * 256 + threadIdx.x;
    if (i < CVT_ITEMS) {
      f32x4 v = __builtin_nontemporal_load((const f32x4*)(x + i * 4));
      ushort4 o = make_ushort4(f2bf(v.x), f2bf(v.y), f2bf(v.z), f2bf(v.w));
      *(ushort4*)(xb + i * 4) = o;
    }
    return;
  }
  bid -= CVT_NB;
  if (bid < PACK1_NB) { pack_w_section(Wl1, Wr1, wcat1, 96, 128, bid); return; }
  bid -= PACK1_NB;
  if (bid < PACK2_NB) { pack_w_section(Wl2, Wr2, wcat2, 128, 128, bid); return; }
  bid -= PACK2_NB;
  pack_w_section(Wl3, Wr3, wcat3, 128, 64, bid);
}

// ---------------- CSR build: LDS counting sort, zero global atomics ----------------

__global__ __launch_bounds__(256) void hist_lds(const int* __restrict__ dst,
                                                ushort* __restrict__ hist_g) {
  __shared__ unsigned hist[HALF_WORDS];
  for (int j = threadIdx.x; j < HALF_WORDS; j += 256) hist[j] = 0;
  __syncthreads();
  int b = blockIdx.x >> 1, r = blockIdx.x & 1;
  int base = b * CH;
  for (int i = threadIdx.x; i < CH; i += 256) {
    int d = __builtin_nontemporal_load(dst + base + i);
    unsigned ld = (unsigned)(d - r * RSZ);
    if (ld < RSZ) atomicAdd(&hist[ld >> 1], (ld & 1) ? 65536u : 1u);
  }
  __syncthreads();
  unsigned* outp = (unsigned*)(hist_g + (size_t)b * N_NODES + r * RSZ);
  for (int j = threadIdx.x; j < HALF_WORDS; j += 256) outp[j] = hist[j];
}

__device__ __forceinline__ int block_excl_scan_256(int v, int tid, int* tot_out) {
  __shared__ int ws[4];
  int lane = tid & 63, wid = tid >> 6;
  int incl = v;
  #pragma unroll
  for (int off = 1; off < 64; off <<= 1) {
    int t = __shfl_up(incl, off);
    if (lane >= off) incl += t;
  }
  if (lane == 63) ws[wid] = incl;
  __syncthreads();
  int woff = 0;
  #pragma unroll
  for (int w = 0; w < 4; w++) woff += (w < wid) ? ws[w] : 0;
  *tot_out = ws[0] + ws[1] + ws[2] + ws[3];
  return woff + incl - v;
}

__global__ __launch_bounds__(256) void scanA(const ushort* __restrict__ hist_g,
                                             ushort* __restrict__ cum_g,
                                             int* __restrict__ rowptr,
                                             int* __restrict__ blocksum, int n) {
  int i = blockIdx.x * 256 + threadIdx.x;
  int run = 0;
  if (i < n) {
    #pragma unroll 4
    for (int b = 0; b < NB_E; b++) {
      size_t o = (size_t)b * N_NODES + i;
      int c = hist_g[o];
      cum_g[o] = (ushort)run;
      run += c;
    }
  }
  int tot;
  int excl = block_excl_scan_256(run, threadIdx.x, &tot);
  if (i < n) rowptr[i] = excl;
  if (threadIdx.x == 0) blocksum[blockIdx.x] = tot;
}

// merged scanB+scanC: every block redundantly scans the SCAN_NB block sums.
__global__ __launch_bounds__(256) void scanBC(const int* __restrict__ blocksum,
                                              int* __restrict__ rowptr, int n) {
  __shared__ int exls[256];
  int tid = threadIdx.x;
  int v = (tid < SCAN_NB) ? blocksum[tid] : 0;
  int tot;
  int excl = block_excl_scan_256(v, tid, &tot);
  exls[tid] = excl;
  __syncthreads();
  int myoff = exls[blockIdx.x];
  int i = blockIdx.x * 256 + tid;
  if (i < n) rowptr[i] += myoff;
  if (blockIdx.x == 0 && tid == 0) rowptr[n] = tot;
}

__global__ __launch_bounds__(256) void fill_lds(const int* __restrict__ src,
                                                const int* __restrict__ dst,
                                                const ushort* __restrict__ cum_g,
                                                const int* __restrict__ rowptr,
                                                ushort* __restrict__ csr) {
  __shared__ unsigned cur[HALF_WORDS];
  int b = blockIdx.x >> 1, r = blockIdx.x & 1;
  const unsigned* cg = (const unsigned*)(cum_g + (size_t)b * N_NODES + r * RSZ);
  for (int j = threadIdx.x; j < HALF_WORDS; j += 256) cur[j] = cg[j];
  __syncthreads();
  int base = b * CH;
  for (int i = threadIdx.x; i < CH; i += 256) {
    int d = __builtin_nontemporal_load(dst + base + i);
    int s = __builtin_nontemporal_load(src + base + i);
    unsigned ld = (unsigned)(d - r * RSZ);
    if (ld < RSZ) {
      unsigned old = atomicAdd(&cur[ld >> 1], (ld & 1) ? 65536u : 1u);
      unsigned loc = (ld & 1) ? (old >> 16) : (old & 0xffffu);
      csr[(size_t)rowptr[d] + loc] = (ushort)s;
    }
  }
}

// ---------------- bf16 MFMA GEMM (no LDS): t = hb @ wcat ----------------
template <int K, int J2>
__global__ __launch_bounds__(256) void gemm_mfma(
    const ushort* __restrict__ hb, const ushort* __restrict__ wcat,
    ushort* __restrict__ tl, ushort* __restrict__ tr, int n) {
  constexpr int Jcat = 2 * J2;
  constexpr int NT = Jcat / 16;
  constexpr int KS = K / 32;

  int tid = threadIdx.x;
  int wid = tid >> 6, lane = tid & 63;
  int rg = lane >> 4, lc = lane & 15;
  int row0 = blockIdx.x * 128;
  int r0 = row0 + wid * 32 + lc;
  int r1 = r0 + 16;
  long ar0 = (long)min(r0, n - 1) * K;
  long ar1 = (long)min(r1, n - 1) * K;

  f32x4 acc[2][NT];
  #pragma unroll
  for (int mt = 0; mt < 2; mt++)
    #pragma unroll
    for (int jt = 0; jt < NT; jt++) acc[mt][jt] = (f32x4){0.f, 0.f, 0.f, 0.f};

  #pragma unroll
  for (int ks = 0; ks < KS; ks++) {
    int koff = ks * 32 + rg * 8;
    short8 a0 = *(const short8*)(hb + ar0 + koff);
    short8 a1 = *(const short8*)(hb + ar1 + koff);
    int kk8 = ks * 4 + rg;
    #pragma unroll
    for (int jt = 0; jt < NT; jt++) {
      short8 bfr = *(const short8*)(wcat + ((size_t)kk8 * Jcat + jt * 16 + lc) * 8);
      acc[0][jt] = __builtin_amdgcn_mfma_f32_16x16x32_bf16(a0, bfr, acc[0][jt], 0, 0, 0);
      acc[1][jt] = __builtin_amdgcn_mfma_f32_16x16x32_bf16(a1, bfr, acc[1][jt], 0, 0, 0);
    }
  }

  // direct epilogue; C/D layout: col = lane&15, row = (lane>>4)*4 + reg
  #pragma unroll
  for (int mt = 0; mt < 2; mt++) {
    int rbase = wid * 32 + mt * 16 + rg * 4;
    #pragma unroll
    for (int jt = 0; jt < NT; jt++) {
      int col = jt * 16 + lc;
      ushort* outp = (col < J2) ? tl : tr;
      int cm = (col < J2) ? col : col - J2;
      #pragma unroll
      for (int r = 0; r < 4; r++) {
        int grow = row0 + rbase + r;
        if (grow < n) outp[(size_t)grow * J2 + cm] = f2bf(acc[mt][jt][r]);
      }
    }
  }
}

// ---------------- aggregate + bias + relu (D=128), 8-deep MLP ----------------
__global__ __launch_bounds__(256) void agg_relu128(
    const ushort* __restrict__ tl, const ushort* __restrict__ tr,
    const float* __restrict__ bias,
    const int* __restrict__ rowptr, const ushort* __restrict__ csr,
    ushort* __restrict__ hout, int n) {
  int node = blockIdx.x * 16 + (threadIdx.x >> 4);
  int lane = threadIdx.x & 15;
  if (node >= n) return;
  int lo = rowptr[node], hi = rowptr[node + 1];
  const ushort* tb = tl + lane * 8;

  float s[8];
  #pragma unroll
  for (int i = 0; i < 8; i++) s[i] = 0.f;

  int e = lo;
  for (; e + 7 < hi; e += 8) {
    ushort8 v[8];
    #pragma unroll
    for (int q = 0; q < 8; q++) v[q] = *(const ushort8*)(tb + (size_t)csr[e + q] * 128);
    #pragma unroll
    for (int q = 0; q < 8; q++)
      #pragma unroll
      for (int i = 0; i < 8; i++) s[i] += bf2f(v[q][i]);
  }
  for (; e + 1 < hi; e += 2) {
    ushort8 v0 = *(const ushort8*)(tb + (size_t)csr[e] * 128);
    ushort8 v1 = *(const ushort8*)(tb + (size_t)csr[e + 1] * 128);
    #pragma unroll
    for (int i = 0; i < 8; i++) s[i] += bf2f(v0[i]) + bf2f(v1[i]);
  }
  if (e < hi) {
    ushort8 v0 = *(const ushort8*)(tb + (size_t)csr[e] * 128);
    #pragma unroll
    for (int i = 0; i < 8; i++) s[i] += bf2f(v0[i]);
  }

  int deg = hi - lo;
  float inv = (deg > 0) ? 1.f / (float)deg : 0.f;
  ushort8 tv = *(const ushort8*)(tr + (size_t)node * 128 + lane * 8);
  float4 b0 = *(const float4*)(bias + lane * 8);
  float4 b1 = *(const float4*)(bias + lane * 8 + 4);
  float bb[8] = {b0.x, b0.y, b0.z, b0.w, b1.x, b1.y, b1.z, b1.w};
  ushort8 o;
  #pragma unroll
  for (int i = 0; i < 8; i++) {
    float v = s[i] * inv + bf2f(tv[i]) + bb[i];
    o[i] = f2bf(v > 0.f ? v : 0.f);
  }
  *(ushort8*)(hout + (size_t)node * 128 + lane * 8) = o;
}

// ---------------- layer 3 aggregate + relu + head (J2=64), 8-deep MLP ----------------
__global__ __launch_bounds__(256) void agg_head(
    const ushort* __restrict__ tl, const ushort* __restrict__ tr,
    const float* __restrict__ bias, const float* __restrict__ Wc,
    const float* __restrict__ bc,
    const int* __restrict__ rowptr, const ushort* __restrict__ csr,
    float* __restrict__ out, int n) {
  int node = blockIdx.x * 32 + (threadIdx.x >> 3);
  int lane = threadIdx.x & 7;
  if (node >= n) return;
  int lo = rowptr[node], hi = rowptr[node + 1];
  const ushort* tb = tl + lane * 8;

  float s[8];
  #pragma unroll
  for (int i = 0; i < 8; i++) s[i] = 0.f;

  int e = lo;
  for (; e + 7 < hi; e += 8) {
    ushort8 v[8];
    #pragma unroll
    for (int q = 0; q < 8; q++) v[q] = *(const ushort8*)(tb + (size_t)csr[e + q] * 64);
    #pragma unroll
    for (int q = 0; q < 8; q++)
      #pragma unroll
      for (int i = 0; i < 8; i++) s[i] += bf2f(v[q][i]);
  }
  for (; e + 1 < hi; e += 2) {
    ushort8 v0 = *(const ushort8*)(tb + (size_t)csr[e] * 64);
    ushort8 v1 = *(const ushort8*)(tb + (size_t)csr[e + 1] * 64);
    #pragma unroll
    for (int i = 0; i < 8; i++) s[i] += bf2f(v0[i]) + bf2f(v1[i]);
  }
  if (e < hi) {
    ushort8 v0 = *(const ushort8*)(tb + (size_t)csr[e] * 64);
    #pragma unroll
    for (int i = 0; i < 8; i++) s[i] += bf2f(v0[i]);
  }

  int deg = hi - lo;
  float inv = (deg > 0) ? 1.f / (float)deg : 0.f;
  ushort8 tv = *(const ushort8*)(tr + (size_t)node * 64 + lane * 8);
  float p0 = 0.f, p1 = 0.f;
  #pragma unroll
  for (int i = 0; i < 8; i++) {
    int k = lane * 8 + i;
    float v = s[i] * inv + bf2f(tv[i]) + bias[k];
    v = v > 0.f ? v : 0.f;
    p0 += v * Wc[k * 2 + 0];
    p1 += v * Wc[k * 2 + 1];
  }
  #pragma unroll
  for (int off = 1; off < 8; off <<= 1) {
    p0 += __shfl_xor(p0, off);
    p1 += __shfl_xor(p1, off);
  }
  if (lane == 0) {
    out[(size_t)node * 2 + 0] = p0 + bc[0];
    out[(size_t)node * 2 + 1] = p1 + bc[1];
  }
}

extern "C" void kernel_launch(void* const* d_in, const int* in_sizes, int n_in,
                              void* d_out, int out_size, void* d_ws, size_t ws_size,
                              hipStream_t stream) {
  const float* x   = (const float*)d_in[0];
  const int*   ei  = (const int*)d_in[1];
  const float* Wl1 = (const float*)d_in[2];
  const float* Wr1 = (const float*)d_in[3];
  const float* b1  = (const float*)d_in[4];
  const float* Wl2 = (const float*)d_in[5];
  const float* Wr2 = (const float*)d_in[6];
  const float* b2  = (const float*)d_in[7];
  const float* Wl3 = (const float*)d_in[8];
  const float* Wr3 = (const float*)d_in[9];
  const float* b3  = (const float*)d_in[10];
  const float* Wc  = (const float*)d_in[11];
  const float* bc  = (const float*)d_in[12];
  float* out = (float*)d_out;

  const int* src = ei;
  const int* dst = ei + N_EDGES;

  char* ws = (char*)d_ws;
  size_t off = 0;
  auto alloc = [&](size_t bytes) -> void* {
    void* p = ws + off;
    off += (bytes + 255) & ~(size_t)255;
    return p;
  };
  int*    rowptr   = (int*)alloc((N_NODES + 1) * sizeof(int));
  ushort* csr      = (ushort*)alloc(N_EDGES * sizeof(ushort));
  int*    blocksum = (int*)alloc(256 * sizeof(int));
  ushort* hist_g   = (ushort*)alloc((size_t)NB_E * N_NODES * 2);   // 6.4MB, dedicated
  ushort* cum_g    = (ushort*)alloc((size_t)NB_E * N_NODES * 2);   // 6.4MB, dedicated
  ushort* xb       = (ushort*)alloc((size_t)N_NODES * 96 * 2);
  ushort* wcat1    = (ushort*)alloc((size_t)96 * 256 * 2);
  ushort* wcat2    = (ushort*)alloc((size_t)128 * 256 * 2);
  ushort* wcat3    = (ushort*)alloc((size_t)128 * 128 * 2);
  ushort* tl       = (ushort*)alloc((size_t)N_NODES * 128 * 2);
  ushort* tr       = (ushort*)alloc((size_t)N_NODES * 128 * 2);
  ushort* hA       = (ushort*)alloc((size_t)N_NODES * 128 * 2);
  ushort* hB       = (ushort*)alloc((size_t)N_NODES * 128 * 2);
  (void)ws_size; (void)n_in; (void)in_sizes; (void)out_size;

  prep_kernel<<<PREP_NB, 256, 0, stream>>>(x, xb,
                                           Wl1, Wr1, wcat1,
                                           Wl2, Wr2, wcat2,
                                           Wl3, Wr3, wcat3);
  hist_lds<<<CSRB, 256, 0, stream>>>(dst, hist_g);
  scanA<<<SCAN_NB, 256, 0, stream>>>(hist_g, cum_g, rowptr, blocksum, N_NODES);
  scanBC<<<SCAN_NB, 256, 0, stream>>>(blocksum, rowptr, N_NODES);
  fill_lds<<<CSRB, 256, 0, stream>>>(src, dst, cum_g, rowptr, csr);

  const int agg_grid  = (N_NODES + 15) / 16;     // 3125
  const int head_grid = (N_NODES + 31) / 32;

  gemm_mfma<96, 128><<<GEMM_NB, 256, 0, stream>>>(xb, wcat1, tl, tr, N_NODES);
  agg_relu128<<<agg_grid, 256, 0, stream>>>(tl, tr, b1, rowptr, csr, hA, N_NODES);
  gemm_mfma<128, 128><<<GEMM_NB, 256, 0, stream>>>(hA, wcat2, tl, tr, N_NODES);
  agg_relu128<<<agg_grid, 256, 0, stream>>>(tl, tr, b2, rowptr, csr, hB, N_NODES);
  gemm_mfma<128, 64><<<GEMM_NB, 256, 0, stream>>>(hB, wcat3, tl, tr, N_NODES);
  agg_head<<<head_grid, 256, 0, stream>>>(tl, tr, b3, Wc, bc, rowptr, csr, out, N_NODES);
}

// Round 15
// 168.219 us; speedup vs baseline: 1.2850x; 1.2850x over previous
//
#include <hip/hip_runtime.h>

#define N_NODES 50000
#define N_EDGES 800000
#define SCAN_NB ((N_NODES + 255) / 256)

// CSR build decomposition: 64 edge chunks x 4 node quarter-ranges
#define NB_E 64
#define CH (N_EDGES / NB_E)            // 12500 edges per chunk
#define CH4 (CH / 4)                   // 3125 int4 groups per chunk
#define NRANGE 4
#define RSZ (N_NODES / NRANGE)         // 12500 nodes per range
#define HALF_WORDS (RSZ / 2)           // 6250 u32 = 25KB LDS
#define CSRB (NB_E * NRANGE)           // 256 blocks for hist/fill

// prep sections (no-LDS kernel: cvt + weight packs)
#define CVT_ITEMS  (N_NODES * 96 / 4)
#define CVT_NB  ((CVT_ITEMS + 255) / 256)
#define PACK1_NB 12
#define PACK2_NB 16
#define PACK3_NB 8
#define PREP_NB (CVT_NB + PACK1_NB + PACK2_NB + PACK3_NB)

#define GEMM_NB ((N_NODES + 127) / 128)   // 391

typedef __attribute__((ext_vector_type(8))) short short8;
typedef __attribute__((ext_vector_type(8))) unsigned short ushort8;
typedef __attribute__((ext_vector_type(4))) float f32x4;
typedef __attribute__((ext_vector_type(4))) int int4v;

__device__ __forceinline__ float bf2f(unsigned short u) {
  unsigned int x = ((unsigned int)u) << 16;
  return __builtin_bit_cast(float, x);
}
__device__ __forceinline__ unsigned short f2bf(float f) {
  unsigned int x = __builtin_bit_cast(unsigned int, f);
  unsigned int r = x + 0x7FFFu + ((x >> 16) & 1u);
  return (unsigned short)(r >> 16);
}

// ---------------- prep: cvt_x | pack_w x3 (no LDS) ----------------

__device__ __forceinline__ void pack_w_section(const float* __restrict__ Wl,
                                               const float* __restrict__ Wr,
                                               ushort* __restrict__ wcat,
                                               int K, int J2, int bid) {
  int idx = bid * 256 + threadIdx.x;
  int Jcat = 2 * J2;
  int total = (K / 8) * Jcat;
  if (idx >= total) return;
  int kk8 = idx / Jcat, j = idx % Jcat;
  const float* W = (j < J2) ? Wl : Wr;
  int jj = (j < J2) ? j : j - J2;
  ushort8 v;
  #pragma unroll
  for (int i = 0; i < 8; i++) v[i] = f2bf(W[(kk8 * 8 + i) * J2 + jj]);
  *(ushort8*)(wcat + (size_t)idx * 8) = v;
}

__global__ __launch_bounds__(256) void prep_kernel(
    const float* __restrict__ x, ushort* __restrict__ xb,
    const float* __restrict__ Wl1, const float* __restrict__ Wr1, ushort* __restrict__ wcat1,
    const float* __restrict__ Wl2, const float* __restrict__ Wr2, ushort* __restrict__ wcat2,
    const float* __restrict__ Wl3, const float* __restrict__ Wr3, ushort* __restrict__ wcat3) {
  int bid = blockIdx.x;
  if (bid < CVT_NB) {
    int i = bid * 256 + threadIdx.x;
    if (i < CVT_ITEMS) {
      f32x4 v = __builtin_nontemporal_load((const f32x4*)(x + i * 4));
      ushort4 o = make_ushort4(f2bf(v.x), f2bf(v.y), f2bf(v.z), f2bf(v.w));
      *(ushort4*)(xb + i * 4) = o;
    }
    return;
  }
  bid -= CVT_NB;
  if (bid < PACK1_NB) { pack_w_section(Wl1, Wr1, wcat1, 96, 128, bid); return; }
  bid -= PACK1_NB;
  if (bid < PACK2_NB) { pack_w_section(Wl2, Wr2, wcat2, 128, 128, bid); return; }
  bid -= PACK2_NB;
  pack_w_section(Wl3, Wr3, wcat3, 128, 64, bid);
}

// ---------------- CSR build: LDS counting sort, zero global atomics ----------------
// Block (b = bid>>2, r = bid&3): edge chunk b, node range [r*12500,(r+1)*12500).
// 512 threads, int4 edge loads (4 edges/thread/iter) for ILP.

__global__ __launch_bounds__(512) void hist_lds(const int* __restrict__ dst,
                                                ushort* __restrict__ hist_g) {
  __shared__ unsigned hist[HALF_WORDS];
  for (int j = threadIdx.x; j < HALF_WORDS; j += 512) hist[j] = 0;
  __syncthreads();
  int b = blockIdx.x >> 2, r = blockIdx.x & 3;
  const int4v* dp = (const int4v*)(dst + b * CH);
  for (int i = threadIdx.x; i < CH4; i += 512) {
    int4v d = dp[i];
    unsigned l0 = (unsigned)(d.x - r * RSZ);
    unsigned l1 = (unsigned)(d.y - r * RSZ);
    unsigned l2 = (unsigned)(d.z - r * RSZ);
    unsigned l3 = (unsigned)(d.w - r * RSZ);
    if (l0 < RSZ) atomicAdd(&hist[l0 >> 1], (l0 & 1) ? 65536u : 1u);
    if (l1 < RSZ) atomicAdd(&hist[l1 >> 1], (l1 & 1) ? 65536u : 1u);
    if (l2 < RSZ) atomicAdd(&hist[l2 >> 1], (l2 & 1) ? 65536u : 1u);
    if (l3 < RSZ) atomicAdd(&hist[l3 >> 1], (l3 & 1) ? 65536u : 1u);
  }
  __syncthreads();
  unsigned* outp = (unsigned*)(hist_g + (size_t)b * N_NODES + r * RSZ);
  for (int j = threadIdx.x; j < HALF_WORDS; j += 512) outp[j] = hist[j];
}

__device__ __forceinline__ int block_excl_scan_256(int v, int tid, int* tot_out) {
  __shared__ int ws[4];
  int lane = tid & 63, wid = tid >> 6;
  int incl = v;
  #pragma unroll
  for (int off = 1; off < 64; off <<= 1) {
    int t = __shfl_up(incl, off);
    if (lane >= off) incl += t;
  }
  if (lane == 63) ws[wid] = incl;
  __syncthreads();
  int woff = 0;
  #pragma unroll
  for (int w = 0; w < 4; w++) woff += (w < wid) ? ws[w] : 0;
  *tot_out = ws[0] + ws[1] + ws[2] + ws[3];
  return woff + incl - v;
}

__global__ __launch_bounds__(256) void scanA(const ushort* __restrict__ hist_g,
                                             ushort* __restrict__ cum_g,
                                             int* __restrict__ rowptr,
                                             int* __restrict__ blocksum, int n) {
  int i = blockIdx.x * 256 + threadIdx.x;
  int run = 0;
  if (i < n) {
    #pragma unroll 4
    for (int b = 0; b < NB_E; b++) {
      size_t o = (size_t)b * N_NODES + i;
      int c = hist_g[o];
      cum_g[o] = (ushort)run;
      run += c;
    }
  }
  int tot;
  int excl = block_excl_scan_256(run, threadIdx.x, &tot);
  if (i < n) rowptr[i] = excl;
  if (threadIdx.x == 0) blocksum[blockIdx.x] = tot;
}

// merged scanB+scanC: every block redundantly scans the SCAN_NB block sums.
__global__ __launch_bounds__(256) void scanBC(const int* __restrict__ blocksum,
                                              int* __restrict__ rowptr, int n) {
  __shared__ int exls[256];
  int tid = threadIdx.x;
  int v = (tid < SCAN_NB) ? blocksum[tid] : 0;
  int tot;
  int excl = block_excl_scan_256(v, tid, &tot);
  exls[tid] = excl;
  __syncthreads();
  int myoff = exls[blockIdx.x];
  int i = blockIdx.x * 256 + tid;
  if (i < n) rowptr[i] += myoff;
  if (blockIdx.x == 0 && tid == 0) rowptr[n] = tot;
}

__global__ __launch_bounds__(512) void fill_lds(const int* __restrict__ src,
                                                const int* __restrict__ dst,
                                                const ushort* __restrict__ cum_g,
                                                const int* __restrict__ rowptr,
                                                ushort* __restrict__ csr) {
  __shared__ unsigned cur[HALF_WORDS];
  int b = blockIdx.x >> 2, r = blockIdx.x & 3;
  const unsigned* cg = (const unsigned*)(cum_g + (size_t)b * N_NODES + r * RSZ);
  for (int j = threadIdx.x; j < HALF_WORDS; j += 512) cur[j] = cg[j];
  __syncthreads();
  const int4v* dp = (const int4v*)(dst + b * CH);
  const int4v* sp = (const int4v*)(src + b * CH);
  for (int i = threadIdx.x; i < CH4; i += 512) {
    int4v d = dp[i];
    int4v s = sp[i];
    #pragma unroll
    for (int q = 0; q < 4; q++) {
      int dv = (q == 0) ? d.x : (q == 1) ? d.y : (q == 2) ? d.z : d.w;
      int sv = (q == 0) ? s.x : (q == 1) ? s.y : (q == 2) ? s.z : s.w;
      unsigned ld = (unsigned)(dv - r * RSZ);
      if (ld < RSZ) {
        unsigned old = atomicAdd(&cur[ld >> 1], (ld & 1) ? 65536u : 1u);
        unsigned loc = (ld & 1) ? (old >> 16) : (old & 0xffffu);
        csr[(size_t)rowptr[dv] + loc] = (ushort)sv;
      }
    }
  }
}

// ---------------- bf16 MFMA GEMM (no LDS): t = hb @ wcat ----------------
template <int K, int J2>
__global__ __launch_bounds__(256) void gemm_mfma(
    const ushort* __restrict__ hb, const ushort* __restrict__ wcat,
    ushort* __restrict__ tl, ushort* __restrict__ tr, int n) {
  constexpr int Jcat = 2 * J2;
  constexpr int NT = Jcat / 16;
  constexpr int KS = K / 32;

  int tid = threadIdx.x;
  int wid = tid >> 6, lane = tid & 63;
  int rg = lane >> 4, lc = lane & 15;
  int row0 = blockIdx.x * 128;
  int r0 = row0 + wid * 32 + lc;
  int r1 = r0 + 16;
  long ar0 = (long)min(r0, n - 1) * K;
  long ar1 = (long)min(r1, n - 1) * K;

  f32x4 acc[2][NT];
  #pragma unroll
  for (int mt = 0; mt < 2; mt++)
    #pragma unroll
    for (int jt = 0; jt < NT; jt++) acc[mt][jt] = (f32x4){0.f, 0.f, 0.f, 0.f};

  #pragma unroll
  for (int ks = 0; ks < KS; ks++) {
    int koff = ks * 32 + rg * 8;
    short8 a0 = *(const short8*)(hb + ar0 + koff);
    short8 a1 = *(const short8*)(hb + ar1 + koff);
    int kk8 = ks * 4 + rg;
    #pragma unroll
    for (int jt = 0; jt < NT; jt++) {
      short8 bfr = *(const short8*)(wcat + ((size_t)kk8 * Jcat + jt * 16 + lc) * 8);
      acc[0][jt] = __builtin_amdgcn_mfma_f32_16x16x32_bf16(a0, bfr, acc[0][jt], 0, 0, 0);
      acc[1][jt] = __builtin_amdgcn_mfma_f32_16x16x32_bf16(a1, bfr, acc[1][jt], 0, 0, 0);
    }
  }

  // direct epilogue; C/D layout: col = lane&15, row = (lane>>4)*4 + reg
  #pragma unroll
  for (int mt = 0; mt < 2; mt++) {
    int rbase = wid * 32 + mt * 16 + rg * 4;
    #pragma unroll
    for (int jt = 0; jt < NT; jt++) {
      int col = jt * 16 + lc;
      ushort* outp = (col < J2) ? tl : tr;
      int cm = (col < J2) ? col : col - J2;
      #pragma unroll
      for (int r = 0; r < 4; r++) {
        int grow = row0 + rbase + r;
        if (grow < n) outp[(size_t)grow * J2 + cm] = f2bf(acc[mt][jt][r]);
      }
    }
  }
}

// ---------------- aggregate + bias + relu (D=128), 8-deep MLP ----------------
__global__ __launch_bounds__(256) void agg_relu128(
    const ushort* __restrict__ tl, const ushort* __restrict__ tr,
    const float* __restrict__ bias,
    const int* __restrict__ rowptr, const ushort* __restrict__ csr,
    ushort* __restrict__ hout, int n) {
  int node = blockIdx.x * 16 + (threadIdx.x >> 4);
  int lane = threadIdx.x & 15;
  if (node >= n) return;
  int lo = rowptr[node], hi = rowptr[node + 1];
  const ushort* tb = tl + lane * 8;

  float s[8];
  #pragma unroll
  for (int i = 0; i < 8; i++) s[i] = 0.f;

  int e = lo;
  for (; e + 7 < hi; e += 8) {
    ushort8 v[8];
    #pragma unroll
    for (int q = 0; q < 8; q++) v[q] = *(const ushort8*)(tb + (size_t)csr[e + q] * 128);
    #pragma unroll
    for (int q = 0; q < 8; q++)
      #pragma unroll
      for (int i = 0; i < 8; i++) s[i] += bf2f(v[q][i]);
  }
  for (; e + 1 < hi; e += 2) {
    ushort8 v0 = *(const ushort8*)(tb + (size_t)csr[e] * 128);
    ushort8 v1 = *(const ushort8*)(tb + (size_t)csr[e + 1] * 128);
    #pragma unroll
    for (int i = 0; i < 8; i++) s[i] += bf2f(v0[i]) + bf2f(v1[i]);
  }
  if (e < hi) {
    ushort8 v0 = *(const ushort8*)(tb + (size_t)csr[e] * 128);
    #pragma unroll
    for (int i = 0; i < 8; i++) s[i] += bf2f(v0[i]);
  }

  int deg = hi - lo;
  float inv = (deg > 0) ? 1.f / (float)deg : 0.f;
  ushort8 tv = *(const ushort8*)(tr + (size_t)node * 128 + lane * 8);
  float4 b0 = *(const float4*)(bias + lane * 8);
  float4 b1 = *(const float4*)(bias + lane * 8 + 4);
  float bb[8] = {b0.x, b0.y, b0.z, b0.w, b1.x, b1.y, b1.z, b1.w};
  ushort8 o;
  #pragma unroll
  for (int i = 0; i < 8; i++) {
    float v = s[i] * inv + bf2f(tv[i]) + bb[i];
    o[i] = f2bf(v > 0.f ? v : 0.f);
  }
  *(ushort8*)(hout + (size_t)node * 128 + lane * 8) = o;
}

// ---------------- layer 3 aggregate + relu + head (J2=64), 8-deep MLP ----------------
__global__ __launch_bounds__(256) void agg_head(
    const ushort* __restrict__ tl, const ushort* __restrict__ tr,
    const float* __restrict__ bias, const float* __restrict__ Wc,
    const float* __restrict__ bc,
    const int* __restrict__ rowptr, const ushort* __restrict__ csr,
    float* __restrict__ out, int n) {
  int node = blockIdx.x * 32 + (threadIdx.x >> 3);
  int lane = threadIdx.x & 7;
  if (node >= n) return;
  int lo = rowptr[node], hi = rowptr[node + 1];
  const ushort* tb = tl + lane * 8;

  float s[8];
  #pragma unroll
  for (int i = 0; i < 8; i++) s[i] = 0.f;

  int e = lo;
  for (; e + 7 < hi; e += 8) {
    ushort8 v[8];
    #pragma unroll
    for (int q = 0; q < 8; q++) v[q] = *(const ushort8*)(tb + (size_t)csr[e + q] * 64);
    #pragma unroll
    for (int q = 0; q < 8; q++)
      #pragma unroll
      for (int i = 0; i < 8; i++) s[i] += bf2f(v[q][i]);
  }
  for (; e + 1 < hi; e += 2) {
    ushort8 v0 = *(const ushort8*)(tb + (size_t)csr[e] * 64);
    ushort8 v1 = *(const ushort8*)(tb + (size_t)csr[e + 1] * 64);
    #pragma unroll
    for (int i = 0; i < 8; i++) s[i] += bf2f(v0[i]) + bf2f(v1[i]);
  }
  if (e < hi) {
    ushort8 v0 = *(const ushort8*)(tb + (size_t)csr[e] * 64);
    #pragma unroll
    for (int i = 0; i < 8; i++) s[i] += bf2f(v0[i]);
  }

  int deg = hi - lo;
  float inv = (deg > 0) ? 1.f / (float)deg : 0.f;
  ushort8 tv = *(const ushort8*)(tr + (size_t)node * 64 + lane * 8);
  float p0 = 0.f, p1 = 0.f;
  #pragma unroll
  for (int i = 0; i < 8; i++) {
    int k = lane * 8 + i;
    float v = s[i] * inv + bf2f(tv[i]) + bias[k];
    v = v > 0.f ? v : 0.f;
    p0 += v * Wc[k * 2 + 0];
    p1 += v * Wc[k * 2 + 1];
  }
  #pragma unroll
  for (int off = 1; off < 8; off <<= 1) {
    p0 += __shfl_xor(p0, off);
    p1 += __shfl_xor(p1, off);
  }
  if (lane == 0) {
    out[(size_t)node * 2 + 0] = p0 + bc[0];
    out[(size_t)node * 2 + 1] = p1 + bc[1];
  }
}

extern "C" void kernel_launch(void* const* d_in, const int* in_sizes, int n_in,
                              void* d_out, int out_size, void* d_ws, size_t ws_size,
                              hipStream_t stream) {
  const float* x   = (const float*)d_in[0];
  const int*   ei  = (const int*)d_in[1];
  const float* Wl1 = (const float*)d_in[2];
  const float* Wr1 = (const float*)d_in[3];
  const float* b1  = (const float*)d_in[4];
  const float* Wl2 = (const float*)d_in[5];
  const float* Wr2 = (const float*)d_in[6];
  const float* b2  = (const float*)d_in[7];
  const float* Wl3 = (const float*)d_in[8];
  const float* Wr3 = (const float*)d_in[9];
  const float* b3  = (const float*)d_in[10];
  const float* Wc  = (const float*)d_in[11];
  const float* bc  = (const float*)d_in[12];
  float* out = (float*)d_out;

  const int* src = ei;
  const int* dst = ei + N_EDGES;

  char* ws = (char*)d_ws;
  size_t off = 0;
  auto alloc = [&](size_t bytes) -> void* {
    void* p = ws + off;
    off += (bytes + 255) & ~(size_t)255;
    return p;
  };
  int*    rowptr   = (int*)alloc((N_NODES + 1) * sizeof(int));
  ushort* csr      = (ushort*)alloc(N_EDGES * sizeof(ushort));
  int*    blocksum = (int*)alloc(256 * sizeof(int));
  ushort* hist_g   = (ushort*)alloc((size_t)NB_E * N_NODES * 2);   // 6.4MB, dedicated
  ushort* cum_g    = (ushort*)alloc((size_t)NB_E * N_NODES * 2);   // 6.4MB, dedicated
  ushort* xb       = (ushort*)alloc((size_t)N_NODES * 96 * 2);
  ushort* wcat1    = (ushort*)alloc((size_t)96 * 256 * 2);
  ushort* wcat2    = (ushort*)alloc((size_t)128 * 256 * 2);
  ushort* wcat3    = (ushort*)alloc((size_t)128 * 128 * 2);
  ushort* tl       = (ushort*)alloc((size_t)N_NODES * 128 * 2);
  ushort* tr       = (ushort*)alloc((size_t)N_NODES * 128 * 2);
  ushort* hA       = (ushort*)alloc((size_t)N_NODES * 128 * 2);
  ushort* hB       = (ushort*)alloc((size_t)N_NODES * 128 * 2);
  (void)ws_size; (void)n_in; (void)in_sizes; (void)out_size;

  prep_kernel<<<PREP_NB, 256, 0, stream>>>(x, xb,
                                           Wl1, Wr1, wcat1,
                                           Wl2, Wr2, wcat2,
                                           Wl3, Wr3, wcat3);
  hist_lds<<<CSRB, 512, 0, stream>>>(dst, hist_g);
  scanA<<<SCAN_NB, 256, 0, stream>>>(hist_g, cum_g, rowptr, blocksum, N_NODES);
  scanBC<<<SCAN_NB, 256, 0, stream>>>(blocksum, rowptr, N_NODES);
  fill_lds<<<CSRB, 512, 0, stream>>>(src, dst, cum_g, rowptr, csr);

  const int agg_grid  = (N_NODES + 15) / 16;     // 3125
  const int head_grid = (N_NODES + 31) / 32;

  gemm_mfma<96, 128><<<GEMM_NB, 256, 0, stream>>>(xb, wcat1, tl, tr, N_NODES);
  agg_relu128<<<agg_grid, 256, 0, stream>>>(tl, tr, b1, rowptr, csr, hA, N_NODES);
  gemm_mfma<128, 128><<<GEMM_NB, 256, 0, stream>>>(hA, wcat2, tl, tr, N_NODES);
  agg_relu128<<<agg_grid, 256, 0, stream>>>(tl, tr, b2, rowptr, csr, hB, N_NODES);
  gemm_mfma<128, 64><<<GEMM_NB, 256, 0, stream>>>(hB, wcat3, tl, tr, N_NODES);
  agg_head<<<head_grid, 256, 0, stream>>>(tl, tr, b3, Wc, bc, rowptr, csr, out, N_NODES);
}